// Round 2
// baseline (3542.254 us; speedup 1.0000x reference)
//
#include <hip/hip_runtime.h>

#define BLK   256
#define Wd    128
#define Hd    128
#define Dd    128
#define NSAMP 8
#define NPS   (Wd * Hd * Dd)      // 2^21 voxels per sample
#define BN    (NSAMP * NPS)       // 2^24 total
#define NBLK  (BN / BLK)          // 65,536 blocks

// ---------------- union-find primitives (lock-free, link-to-min) -----------
// Parent pointers are non-increasing and only roots are re-linked (CAS to a
// strictly smaller index), so chains strictly decrease -> no cycles, find
// terminates, plain-store path halving is race-safe.
__device__ __forceinline__ int find_root(int* __restrict__ L, int x) {
    int p = L[x];
    while (p != x) {
        int gp = L[p];
        if (gp != p) L[x] = gp;   // path halving (x is a non-root: safe)
        x = gp;
        p = L[x];
    }
    return x;
}

__device__ __forceinline__ void unite(int* __restrict__ L, int a, int b) {
    a = find_root(L, a);
    b = find_root(L, b);
    while (a != b) {
        if (a < b) { int t = a; a = b; b = t; }   // a > b: link a under b
        int old = atomicCAS(&L[a], a, b);
        if (old == a) return;
        a = find_root(L, old);
        b = find_root(L, b);
    }
}

// ---------------- kernels ---------------------------------------------------
// May run in-place: L aliases g (read the float, then overwrite with int32).
__global__ void k_init(const float* __restrict__ g, int* __restrict__ L) {
    int i = blockIdx.x * BLK + threadIdx.x;
    float v = g[i];
    L[i] = (v > 0.5f) ? i : -1;
}

__global__ void k_merge(int* __restrict__ L) {
    int i = blockIdx.x * BLK + threadIdx.x;
    if (L[i] < 0) return;                      // background never changes
    int x = i & (Wd - 1);
    int y = (i >> 7) & (Hd - 1);
    int z = (i >> 14) & (Dd - 1);
    if (x > 0 && L[i - 1] >= 0)        unite(L, i, i - 1);
    if (y > 0 && L[i - Wd] >= 0)       unite(L, i, i - Wd);
    if (z > 0 && L[i - Wd * Hd] >= 0)  unite(L, i, i - Wd * Hd);
}

// Find root (with compression), dedupe per-block in a 512-slot LDS hash,
// then flush to a global open-addressing hash (keys=-1 empty).
__global__ void k_count(int* __restrict__ L,
                        int* __restrict__ gk, int* __restrict__ gv,
                        unsigned hmask) {
    __shared__ int hk[512];
    __shared__ int hv[512];
    int t = threadIdx.x;
    hk[t] = -1;        hv[t] = 0;
    hk[t + 256] = -1;  hv[t + 256] = 0;
    __syncthreads();

    int i = blockIdx.x * BLK + t;
    if (L[i] >= 0) {
        int root = find_root(L, i);
        unsigned h = ((unsigned)root * 2654435761u) & 511u;
        for (int probe = 0; probe < 512; ++probe) {      // bounded (<=256 keys)
            int prev = atomicCAS(&hk[h], -1, root);
            if (prev == -1 || prev == root) { atomicAdd(&hv[h], 1); break; }
            h = (h + 1) & 511u;
        }
    }
    __syncthreads();

    for (int s = t; s < 512; s += BLK) {
        int k = hk[s];
        if (k < 0) continue;
        unsigned h = ((unsigned)k * 2654435761u) & hmask;
        for (unsigned probe = 0; probe <= hmask; ++probe) {  // bounded
            int prev = atomicCAS(&gk[h], -1, k);
            if (prev == -1 || prev == k) { atomicAdd(&gv[h], hv[s]); break; }
            h = (h + 1) & hmask;
        }
    }
}

// acc layout: largest[8] | ncomp[8] | total[8]
__global__ void k_reduce(const int* __restrict__ gk, const int* __restrict__ gv,
                         int nslots, int* __restrict__ acc) {
    int i = blockIdx.x * BLK + threadIdx.x;
    if (i >= nslots) return;
    int k = gk[i];
    if (k < 0) return;
    int c = gv[i];
    int b = k >> 21;                 // root index / NPS
    atomicMax(&acc[b], c);
    atomicAdd(&acc[8 + b], 1);
    atomicAdd(&acc[16 + b], c);
}

__global__ void k_final(const int* __restrict__ acc, float* __restrict__ out) {
    if (threadIdx.x == 0 && blockIdx.x == 0) {
        float s = 0.0f;
        for (int b = 0; b < NSAMP; ++b) {
            int largest = acc[b];
            int ncomp   = acc[8 + b];
            int total   = acc[16 + b];
            if (ncomp > 1)
                s += ((float)(total - largest)) / ((float)total + 1e-6f);
        }
        out[0] = 10.0f * s / (float)NSAMP;
    }
}

// ---------------- launch ----------------------------------------------------
extern "C" void kernel_launch(void* const* d_in, const int* in_sizes, int n_in,
                              void* d_out, int out_size, void* d_ws, size_t ws_size,
                              hipStream_t stream) {
    const float* grid = (const float*)d_in[0];
    float* out = (float*)d_out;
    char* ws = (char*)d_ws;

    const size_t LBYTES = (size_t)BN * 4;     // 64 MiB labels

    // Place labels: in d_ws if it fits, else in-place over the input grid
    // (grid is only read once, and the harness restores inputs pre-launch).
    int* labels;
    size_t off = 0;
    if (ws_size >= LBYTES + (1u << 16) * 8 + 256) {
        labels = (int*)ws;
        off = LBYTES;
    } else {
        labels = (int*)d_in[0];
    }

    // Hash: largest power-of-two slot count fitting in remaining ws (8 B/slot
    // + 128 B for acc), capped at 2^22 (~150k expected keys -> tiny load).
    size_t remain = (ws_size > off + 256) ? (ws_size - off - 256) : 0;
    unsigned HS = 1u << 10;
    while ((size_t)(HS << 1) * 8 <= remain && HS < (1u << 22)) HS <<= 1;

    int* gk  = (int*)(ws + off);
    int* gv  = gk + HS;
    int* acc = gv + HS;

    hipMemsetAsync(acc, 0, 96, stream);
    hipMemsetAsync(gk, 0xFF, (size_t)HS * 4, stream);   // keys = -1
    hipMemsetAsync(gv, 0x00, (size_t)HS * 4, stream);

    k_init <<<NBLK, BLK, 0, stream>>>(grid, labels);
    k_merge<<<NBLK, BLK, 0, stream>>>(labels);
    k_count<<<NBLK, BLK, 0, stream>>>(labels, gk, gv, HS - 1);
    k_reduce<<<(HS + BLK - 1) / BLK, BLK, 0, stream>>>(gk, gv, (int)HS, acc);
    k_final<<<1, 64, 0, stream>>>(acc, out);
}

// Round 3
// 2437.871 us; speedup vs baseline: 1.4530x; 1.4530x over previous
//
#include <hip/hip_runtime.h>

#define BLK   256
#define Wd    128
#define Hd    128
#define Dd    128
#define NSAMP 8
#define NPS   (Wd * Hd * Dd)      // 2^21 voxels per sample
#define BN    (NSAMP * NPS)       // 2^24 total
#define NBLK  (BN / BLK)          // 65,536 blocks

// ---------------- union-find primitives (lock-free, link-to-min) -----------
// Parent pointers are non-increasing and only roots are re-linked (CAS to a
// strictly smaller index), so chains strictly decrease -> no cycles, find
// terminates, plain-store path halving is race-safe.
__device__ __forceinline__ int find_root(int* __restrict__ L, int x) {
    int p = L[x];
    while (p != x) {
        int gp = L[p];
        if (gp != p) L[x] = gp;   // path halving (x is a non-root: safe)
        x = gp;
        p = L[x];
    }
    return x;
}

__device__ __forceinline__ void unite(int* __restrict__ L, int a, int b) {
    a = find_root(L, a);
    b = find_root(L, b);
    while (a != b) {
        if (a < b) { int t = a; a = b; b = t; }   // a > b: link a under b
        int old = atomicCAS(&L[a], a, b);
        if (old == a) return;
        a = find_root(L, old);
        b = find_root(L, b);
    }
}

// ---------------- kernels ---------------------------------------------------
__global__ void k_init(const float* __restrict__ g, int* __restrict__ L) {
    int i = blockIdx.x * BLK + threadIdx.x;
    float v = g[i];
    L[i] = (v > 0.5f) ? i : -1;
}

__global__ void k_merge(int* __restrict__ L) {
    int i = blockIdx.x * BLK + threadIdx.x;
    if (L[i] < 0) return;                      // background never changes
    int x = i & (Wd - 1);
    int y = (i >> 7) & (Hd - 1);
    int z = (i >> 14) & (Dd - 1);
    if (x > 0 && L[i - 1] >= 0)        unite(L, i, i - 1);
    if (y > 0 && L[i - Wd] >= 0)       unite(L, i, i - Wd);
    if (z > 0 && L[i - Wd * Hd] >= 0)  unite(L, i, i - Wd * Hd);
}

// Find root (with compression), dedupe per-block in a 512-slot LDS hash,
// then flush to a global open-addressing hash (keys=-1 empty).
__global__ void k_count(int* __restrict__ L,
                        int* __restrict__ gk, int* __restrict__ gv,
                        unsigned hmask) {
    __shared__ int hk[512];
    __shared__ int hv[512];
    int t = threadIdx.x;
    hk[t] = -1;        hv[t] = 0;
    hk[t + 256] = -1;  hv[t + 256] = 0;
    __syncthreads();

    int i = blockIdx.x * BLK + t;
    if (L[i] >= 0) {
        int root = find_root(L, i);
        unsigned h = ((unsigned)root * 2654435761u) & 511u;
        for (int probe = 0; probe < 512; ++probe) {      // bounded (<=256 keys)
            int prev = atomicCAS(&hk[h], -1, root);
            if (prev == -1 || prev == root) { atomicAdd(&hv[h], 1); break; }
            h = (h + 1) & 511u;
        }
    }
    __syncthreads();

    for (int s = t; s < 512; s += BLK) {
        int k = hk[s];
        if (k < 0) continue;
        unsigned h = ((unsigned)k * 2654435761u) & hmask;
        for (unsigned probe = 0; probe <= hmask; ++probe) {  // bounded
            int prev = atomicCAS(&gk[h], -1, k);
            if (prev == -1 || prev == k) { atomicAdd(&gv[h], hv[s]); break; }
            h = (h + 1) & hmask;
        }
    }
}

// Grid-stride hash scan with per-block LDS pre-reduction; only 24 global
// atomics per block (Guideline 12: reduce locally before contended atomics).
// acc layout: largest[8] | ncomp[8] | total[8]
#define RED_BLOCKS 512
__global__ void k_reduce(const int* __restrict__ gk, const int* __restrict__ gv,
                         int nslots, int* __restrict__ acc) {
    __shared__ int s_mx[NSAMP], s_cnt[NSAMP], s_sum[NSAMP];
    int t = threadIdx.x;
    if (t < NSAMP) { s_mx[t] = 0; s_cnt[t] = 0; s_sum[t] = 0; }
    __syncthreads();

    for (int i = blockIdx.x * BLK + t; i < nslots; i += RED_BLOCKS * BLK) {
        int k = gk[i];
        if (k >= 0) {
            int c = gv[i];
            int b = k >> 21;                 // root / NPS -> sample index
            atomicMax(&s_mx[b], c);
            atomicAdd(&s_cnt[b], 1);
            atomicAdd(&s_sum[b], c);
        }
    }
    __syncthreads();

    if (t < NSAMP) {
        if (s_mx[t])  atomicMax(&acc[t], s_mx[t]);
        if (s_cnt[t]) {
            atomicAdd(&acc[NSAMP + t], s_cnt[t]);
            atomicAdd(&acc[2 * NSAMP + t], s_sum[t]);
        }
    }
}

__global__ void k_final(const int* __restrict__ acc, float* __restrict__ out) {
    if (threadIdx.x == 0 && blockIdx.x == 0) {
        float s = 0.0f;
        for (int b = 0; b < NSAMP; ++b) {
            int largest = acc[b];
            int ncomp   = acc[NSAMP + b];
            int total   = acc[2 * NSAMP + b];
            if (ncomp > 1)
                s += ((float)(total - largest)) / ((float)total + 1e-6f);
        }
        out[0] = 10.0f * s / (float)NSAMP;
    }
}

// ---------------- launch ----------------------------------------------------
extern "C" void kernel_launch(void* const* d_in, const int* in_sizes, int n_in,
                              void* d_out, int out_size, void* d_ws, size_t ws_size,
                              hipStream_t stream) {
    const float* grid = (const float*)d_in[0];
    float* out = (float*)d_out;
    char* ws = (char*)d_ws;

    const size_t LBYTES = (size_t)BN * 4;     // 64 MiB labels

    // Place labels: in d_ws if it fits, else in-place over the input grid
    // (grid is only read once, and the harness restores inputs pre-launch).
    int* labels;
    size_t off = 0;
    if (ws_size >= LBYTES + (1u << 16) * 8 + 256) {
        labels = (int*)ws;
        off = LBYTES;
    } else {
        labels = (int*)d_in[0];
    }

    // Hash: largest power-of-two slot count fitting in remaining ws
    // (8 B/slot + 128 B for acc), capped at 2^20 (~200k keys -> load ~0.2).
    size_t remain = (ws_size > off + 256) ? (ws_size - off - 256) : 0;
    unsigned HS = 1u << 10;
    while ((size_t)(HS << 1) * 8 <= remain && HS < (1u << 20)) HS <<= 1;

    int* gk  = (int*)(ws + off);
    int* gv  = gk + HS;
    int* acc = gv + HS;

    hipMemsetAsync(acc, 0, 96, stream);
    hipMemsetAsync(gk, 0xFF, (size_t)HS * 4, stream);   // keys = -1
    hipMemsetAsync(gv, 0x00, (size_t)HS * 4, stream);

    k_init <<<NBLK, BLK, 0, stream>>>(grid, labels);
    k_merge<<<NBLK, BLK, 0, stream>>>(labels);
    k_count<<<NBLK, BLK, 0, stream>>>(labels, gk, gv, HS - 1);
    k_reduce<<<RED_BLOCKS, BLK, 0, stream>>>(gk, gv, (int)HS, acc);
    k_final<<<1, 64, 0, stream>>>(acc, out);
}